// Round 11
// baseline (1343.643 us; speedup 1.0000x reference)
//
#include <hip/hip_runtime.h>

#define BB 64
#define TT 2048
#define II 64
#define HH 256
#define NTHR 256   // 4 waves, 1 wave/SIMD; weights in AGPRs

typedef _Float16 v8h __attribute__((ext_vector_type(8)));
typedef float v4f __attribute__((ext_vector_type(4)));
typedef int v4i __attribute__((ext_vector_type(4)));

#define PK(a, b) __builtin_bit_cast(int, __builtin_amdgcn_cvt_pkrtz((a), (b)))

// Inline-asm MFMA with B operand in AGPR (gfx950 unified RF: A/B may be
// AGPR, cdna4_isa §10). Tied form: acc = A*B + acc (D==C back-to-back
// accumulate is HW-legal — every compiled GEMM emits it nop-free).
#define MFMA_T(acc, a_, b_) \
    asm("v_mfma_f32_16x16x32_f16 %0, %1, %2, %0" : "+v"(acc) : "v"(a_), "a"(b_))
// Init form: acc = A*B + cinit (D != C, no copy; early-clobber keeps D off A/B)
#define MFMA_I(acc, a_, b_, c_) \
    asm("v_mfma_f32_16x16x32_f16 %0, %1, %2, %3" : "=&v"(acc) : "v"(a_), "a"(b_), "v"(c_))

// tanh(x) = 1 - 2/(e^{2x}+1); v_exp + v_rcp, correct limits at +-inf.
__device__ __forceinline__ float ftanh(float x) {
    float e = __expf(2.0f * x);
    return 1.0f - 2.0f * __builtin_amdgcn_rcpf(e + 1.0f);
}

// DPP ctrl: 0xB1 quad ^1, 0x4E quad ^2, 0x141 ROW_HALF_MIRROR (eff ^4 after
// ^1,^2), 0x140 ROW_MIRROR (eff ^8). 16-lane-row scoped -> lane 0 of each
// row ends with the row sum. (Harness-verified R6-R10.)
template <int CTRL>
__device__ __forceinline__ float dpp_add(float v) {
    int s = __builtin_amdgcn_update_dpp(0, __float_as_int(v), CTRL, 0xF, 0xF, true);
    return v + __int_as_float(s);
}

__device__ __forceinline__ v8h xfrag(const float4 s0, const float4 s1) {
    v4i r = {PK(s0.x, s0.y), PK(s0.z, s0.w), PK(s1.x, s1.y), PK(s1.z, s1.w)};
    return __builtin_bit_cast(v8h, r);
}

// R11: 4 waves + AGPR-parked weights. R9/R10 diagnosis: active CUs ~85%
// pipe-busy (VALU 39% + MFMA 45%); VALU is dominated by PER-WAVE duplicated
// overhead (head DPP, xfrag, 64b addressing, masks ~100 instr/wave/step) —
// 8 waves pay it 8x. The 4-wave MFMA variant (R7/R8) failed only on VGPR
// footprint (>256 -> marshalling). Fix: weights live in AGPRs ("+a" pin;
// all MFMAs are inline asm with "a" B-operand), legal on gfx950's unified
// file. 1 wave/SIMD budget 512 regs: ~170 VGPR + 160 AGPR, no spill, no
// per-step moves, lone wave owns its SIMD MFMA pipe. Streams arrival-aware
// (A: x8,x9,h0,h1 / B: h2,h3,h4 / C: h5,h6,h7 per tc). MFMA->VALU readback
// fenced with s_nop 7 x2 threaded through accs (asm is opaque to the
// compiler's hazard inserter). Everything else = R7-R10 passing structure.
__launch_bounds__(NTHR, 1)
__global__ void rnn_fused(const float* __restrict__ x,
                          const float* __restrict__ W_ih,
                          const float* __restrict__ W_hh,
                          const float* __restrict__ b_ih,
                          const float* __restrict__ b_hh,
                          const float* __restrict__ W_fc,
                          const float* __restrict__ b_fc,
                          float* __restrict__ out) {
    __shared__ __align__(16) __fp16 hlds[2][HH];  // 1 KB, double-buffered
    __shared__ float part[TT + 1][4];             // head partials, 32.8 KB

    const int tid  = threadIdx.x;
    const int b    = blockIdx.x;
    const int lane = tid & 63;
    const int w    = tid >> 6;     // wave 0..3: output cols [64w, 64w+64)
    const int g    = lane >> 4;    // 16-lane group 0..3 (k sub-slice)
    const int c16  = lane & 15;

    // ---- B fragments: bf[tc][T]: lane (g,c16) holds
    // W[n = 64w+16tc+c16][k = 32T + 8g + j], j=0..7  (T=8,9 -> W_ih, k-256)
    v8h bf[4][10];   // -> 160 AGPRs (40 aligned quads)
    v4f bvv[4];      // bias splat quads (C-init of stream A), VGPR
    float wf[4];
#pragma unroll
    for (int tc = 0; tc < 4; ++tc) {
        const int n = 64 * w + 16 * tc + c16;
#pragma unroll
        for (int T = 0; T < 8; ++T) {
            const float* wp = W_hh + n * HH + 32 * T + 8 * g;
            const float4 f0 = *(const float4*)wp;
            const float4 f1 = *(const float4*)(wp + 4);
            v4i r = {PK(f0.x, f0.y), PK(f0.z, f0.w), PK(f1.x, f1.y), PK(f1.z, f1.w)};
            bf[tc][T] = __builtin_bit_cast(v8h, r);
        }
#pragma unroll
        for (int T = 8; T < 10; ++T) {
            const float* wp = W_ih + n * II + 32 * (T - 8) + 8 * g;
            const float4 f0 = *(const float4*)wp;
            const float4 f1 = *(const float4*)(wp + 4);
            v4i r = {PK(f0.x, f0.y), PK(f0.z, f0.w), PK(f1.x, f1.y), PK(f1.z, f1.w)};
            bf[tc][T] = __builtin_bit_cast(v8h, r);
        }
        const float bias = b_ih[n] + b_hh[n];
        bvv[tc] = (v4f){bias, bias, bias, bias};
        wf[tc] = W_fc[n];
    }
    // park weights in AGPRs ("+a"): one accvgpr_write burst at init; every
    // consumer below is an "a"-constrained MFMA operand -> stays in AGPR.
#pragma unroll
    for (int tc = 0; tc < 4; ++tc) {
#pragma unroll
        for (int T = 0; T < 10; ++T) asm volatile("" : "+a"(bf[tc][T]));
        asm volatile("" : "+v"(bvv[tc]));
        asm volatile("" : "+v"(wf[tc]));
    }
    v4f zq = (v4f){0.f, 0.f, 0.f, 0.f};  // zero C-quad for streams B/C
    asm volatile("" : "+v"(zq));
    const float bfc = b_fc[0];

    for (int idx = tid; idx < 2 * HH; idx += NTHR)
        ((__fp16*)hlds)[idx] = (__fp16)0;  // h_0 = 0
    __syncthreads();

    const float* xrow = x + (size_t)b * TT * II;
    float* outb = out + (size_t)b * TT;

    // h read base: GROUP-UNIFORM chunk address (broadcast within group,
    // conflict-free, R7-verified); k-tile T at byte offset T*64.
    const char* hrd0 = (const char*)&hlds[0][0] + g * 16;
    const char* hrd1 = (const char*)&hlds[1][0] + g * 16;
    // h write (lanes 0-15 only): col = 64w + 16tc + c16, tc -> +16 halves
    __fp16* hwr0 = &hlds[0][64 * w + c16];
    __fp16* hwr1 = &hlds[1][64 * w + c16];

    // x pipeline: xf8/xf9 = frags for step i; slots A/B raw rows i+1, i+2
    v8h xf8, xf9;
    float4 rA0, rA1, rA2, rA3, rB0, rB1, rB2, rB3;
    {
        const float* x0 = xrow;
        xf8 = xfrag(*(const float4*)(x0 + 8 * g), *(const float4*)(x0 + 8 * g + 4));
        xf9 = xfrag(*(const float4*)(x0 + 32 + 8 * g), *(const float4*)(x0 + 36 + 8 * g));
        const float* x1 = xrow + II;
        rA0 = *(const float4*)(x1 + 8 * g);      rA1 = *(const float4*)(x1 + 8 * g + 4);
        rA2 = *(const float4*)(x1 + 32 + 8 * g); rA3 = *(const float4*)(x1 + 36 + 8 * g);
        const float* x2 = xrow + 2 * II;
        rB0 = *(const float4*)(x2 + 8 * g);      rB1 = *(const float4*)(x2 + 8 * g + 4);
        rB2 = *(const float4*)(x2 + 32 + 8 * g); rB3 = *(const float4*)(x2 + 36 + 8 * g);
    }

    float ph = 0.0f;  // per-lane head partial of previous step (pre-reduce)

#define STEP(I, P, R0, R1, R2, R3)                                             \
    {                                                                          \
        /* issue all 8 h-tile reads in consumption order (conflict-free) */    \
        const char* hrd = (P) ? hrd1 : hrd0;                                   \
        const v8h hv0 = *(const v8h*)(hrd + 0 * 64);                           \
        const v8h hv1 = *(const v8h*)(hrd + 1 * 64);                           \
        const v8h hv2 = *(const v8h*)(hrd + 2 * 64);                           \
        const v8h hv3 = *(const v8h*)(hrd + 3 * 64);                           \
        const v8h hv4 = *(const v8h*)(hrd + 4 * 64);                           \
        const v8h hv5 = *(const v8h*)(hrd + 5 * 64);                           \
        const v8h hv6 = *(const v8h*)(hrd + 6 * 64);                           \
        const v8h hv7 = *(const v8h*)(hrd + 7 * 64);                           \
        /* deferred head of step I-1: 16-lane DPP reduce, fills read latency */\
        if ((I) > 0) {                                                         \
            float hc = ph;                                                     \
            hc = dpp_add<0xB1>(hc);                                            \
            hc = dpp_add<0x4E>(hc);                                            \
            hc = dpp_add<0x141>(hc);                                           \
            hc = dpp_add<0x140>(hc);                                           \
            if (lane == 0) part[I][w] = hc;                                    \
        }                                                                      \
        /* 40 MFMA: per tc 3 arrival-aware streams A(x8,x9,h0,h1) B(h2,h3,h4)*/\
        /* C(h5,h6,h7); issued k-slot-major for cross-tc independence */       \
        v4f aA0, aA1, aA2, aA3, aB0, aB1, aB2, aB3, aC0, aC1, aC2, aC3;        \
        MFMA_I(aA0, xf8, bf[0][8], bvv[0]);                                    \
        MFMA_I(aA1, xf8, bf[1][8], bvv[1]);                                    \
        MFMA_I(aA2, xf8, bf[2][8], bvv[2]);                                    \
        MFMA_I(aA3, xf8, bf[3][8], bvv[3]);                                    \
        MFMA_T(aA0, xf9, bf[0][9]);                                            \
        MFMA_T(aA1, xf9, bf[1][9]);                                            \
        MFMA_T(aA2, xf9, bf[2][9]);                                            \
        MFMA_T(aA3, xf9, bf[3][9]);                                            \
        MFMA_T(aA0, hv0, bf[0][0]);                                            \
        MFMA_T(aA1, hv0, bf[1][0]);                                            \
        MFMA_T(aA2, hv0, bf[2][0]);                                            \
        MFMA_T(aA3, hv0, bf[3][0]);                                            \
        MFMA_I(aB0, hv2, bf[0][2], zq);                                        \
        MFMA_I(aB1, hv2, bf[1][2], zq);                                        \
        MFMA_I(aB2, hv2, bf[2][2], zq);                                        \
        MFMA_I(aB3, hv2, bf[3][2], zq);                                        \
        MFMA_T(aA0, hv1, bf[0][1]);                                            \
        MFMA_T(aA1, hv1, bf[1][1]);                                            \
        MFMA_T(aA2, hv1, bf[2][1]);                                            \
        MFMA_T(aA3, hv1, bf[3][1]);                                            \
        MFMA_T(aB0, hv3, bf[0][3]);                                            \
        MFMA_T(aB1, hv3, bf[1][3]);                                            \
        MFMA_T(aB2, hv3, bf[2][3]);                                            \
        MFMA_T(aB3, hv3, bf[3][3]);                                            \
        MFMA_I(aC0, hv5, bf[0][5], zq);                                        \
        MFMA_I(aC1, hv5, bf[1][5], zq);                                        \
        MFMA_I(aC2, hv5, bf[2][5], zq);                                        \
        MFMA_I(aC3, hv5, bf[3][5], zq);                                        \
        MFMA_T(aB0, hv4, bf[0][4]);                                            \
        MFMA_T(aB1, hv4, bf[1][4]);                                            \
        MFMA_T(aB2, hv4, bf[2][4]);                                            \
        MFMA_T(aB3, hv4, bf[3][4]);                                            \
        MFMA_T(aC0, hv6, bf[0][6]);                                            \
        MFMA_T(aC1, hv6, bf[1][6]);                                            \
        MFMA_T(aC2, hv6, bf[2][6]);                                            \
        MFMA_T(aC3, hv6, bf[3][6]);                                            \
        MFMA_T(aC0, hv7, bf[0][7]);                                            \
        MFMA_T(aC1, hv7, bf[1][7]);                                            \
        MFMA_T(aC2, hv7, bf[2][7]);                                            \
        MFMA_T(aC3, hv7, bf[3][7]);                                            \
        /* x pipeline rotate (overlaps MFMA tail): consume row I+1, load I+3 */\
        xf8 = xfrag(R0, R1);                                                   \
        xf9 = xfrag(R2, R3);                                                   \
        {                                                                      \
            const int rn = ((I) + 3 < TT) ? ((I) + 3) : (TT - 1);              \
            const float* xp = xrow + rn * II;                                  \
            R0 = *(const float4*)(xp + 8 * g);                                 \
            R1 = *(const float4*)(xp + 8 * g + 4);                             \
            R2 = *(const float4*)(xp + 32 + 8 * g);                            \
            R3 = *(const float4*)(xp + 36 + 8 * g);                            \
        }                                                                      \
        /* MFMA->VALU readback fence: asm is opaque to the compiler's hazard */\
        /* inserter; thread accs through s_nop so adds can't be hoisted */     \
        asm volatile("s_nop 7\n\ts_nop 7"                                      \
            : "+v"(aA0), "+v"(aB0), "+v"(aC0), "+v"(aA1), "+v"(aB1),           \
              "+v"(aC1), "+v"(aA2), "+v"(aB2), "+v"(aC2), "+v"(aA3),           \
              "+v"(aB3), "+v"(aC3));                                           \
        const float e0 = (aA0[0] + aB0[0]) + aC0[0];                           \
        const float e1 = (aA1[0] + aB1[0]) + aC1[0];                           \
        const float e2 = (aA2[0] + aB2[0]) + aC2[0];                           \
        const float e3 = (aA3[0] + aB3[0]) + aC3[0];                           \
        const float h0 = ftanh(e0);                                            \
        const float h1 = ftanh(e1);                                            \
        const float h2 = ftanh(e2);                                            \
        const float h3 = ftanh(e3);                                            \
        ph = fmaf(h3, wf[3], fmaf(h2, wf[2], fmaf(h1, wf[1], h0 * wf[0])));    \
        if (lane < 16) {                                                       \
            __fp16* hp = (P) ? hwr0 : hwr1;                                    \
            hp[0]  = (__fp16)h0;                                               \
            hp[16] = (__fp16)h1;                                               \
            hp[32] = (__fp16)h2;                                               \
            hp[48] = (__fp16)h3;                                               \
        }                                                                      \
        /* LDS-only barrier: vmcnt NOT drained (x prefetch spans steps) */     \
        asm volatile("s_waitcnt lgkmcnt(0)\n\ts_barrier" ::: "memory");        \
    }

    for (int ib = 0; ib < TT; ib += 2) {
        STEP(ib, 0, rA0, rA1, rA2, rA3)
        STEP(ib + 1, 1, rB0, rB1, rB2, rB3)
    }
#undef STEP

    // final head (step TT-1) -> part[TT]
    {
        float hc = ph;
        hc = dpp_add<0xB1>(hc);
        hc = dpp_add<0x4E>(hc);
        hc = dpp_add<0x141>(hc);
        hc = dpp_add<0x140>(hc);
        if (lane == 0) part[TT][w] = hc;
    }
    __syncthreads();

    // ---- deferred output head: out[b][i] = sum(part[i+1][0..3]) + bfc ----
    for (int i = tid; i < TT; i += NTHR) {
        const float4 s = *(const float4*)&part[i + 1][0];
        outb[i] = s.x + s.y + s.z + s.w + bfc;
    }
}

extern "C" void kernel_launch(void* const* d_in, const int* in_sizes, int n_in,
                              void* d_out, int out_size, void* d_ws, size_t ws_size,
                              hipStream_t stream) {
    const float* x    = (const float*)d_in[0];
    const float* W_ih = (const float*)d_in[1];
    const float* W_hh = (const float*)d_in[2];
    const float* b_ih = (const float*)d_in[3];
    const float* b_hh = (const float*)d_in[4];
    const float* W_fc = (const float*)d_in[5];
    const float* b_fc = (const float*)d_in[6];
    float* out = (float*)d_out;

    rnn_fused<<<BB, NTHR, 0, stream>>>(x, W_ih, W_hh, b_ih, b_hh, W_fc, b_fc, out);
}